// Round 1
// baseline (385.981 us; speedup 1.0000x reference)
//
#include <hip/hip_runtime.h>
#include <cstdint>
#include <cstddef>

// ---------------------------------------------------------------------------
// TransformerLayer forward on MI355X (gfx950), bf16 MFMA pipeline.
// B=2, S=2048, D=1024, H=16, HD=64.  M = B*S = 4096 rows.
// ---------------------------------------------------------------------------

#define B_ 2
#define S_ 2048
#define D_ 1024
#define H_ 16
#define M_ 4096

typedef __attribute__((ext_vector_type(4))) float  f32x4;
typedef __attribute__((ext_vector_type(8))) __bf16 bf16x8;
typedef __attribute__((ext_vector_type(4))) __bf16 bf16x4;

// async global->LDS copy, 16B per lane. LDS dest must be wave-uniform base +
// lane*16 (we always build linear layouts that satisfy this).
__device__ __forceinline__ void async16(const void* g, void* l) {
    __builtin_amdgcn_global_load_lds(
        (__attribute__((address_space(1))) void*)(g),
        (__attribute__((address_space(3))) void*)(l), 16, 0, 0);
}

// sigmoid(z)*tanh(z) == (1-u)/(1+u^2) with u = exp(-z)
__device__ __forceinline__ float sigtanh(float z) {
    z = fminf(fmaxf(z, -20.f), 20.f);
    float u = __expf(-z);
    return (1.f - u) * __fdividef(1.f, 1.f + u * u);
}

// ---------------------------------------------------------------------------
// GEMM: C[M][N] = epilogue(A[M][K] @ Bt[N][K]^T + bias)
// BM=128, BN=64, BK=32. 4 waves, each 64x32 (4x2 fragments of 16x16).
// EPI: 0 = bias -> bf16
//      1 = leaky_relu(bias, 0.2) -> bf16
//      2 = aux + s*(acc+bias) -> bf16   (gated residual, latent)
//      3 = aux + s*(acc+bias) -> f32    (final output)
// ---------------------------------------------------------------------------
template <int EPI>
__global__ __launch_bounds__(256) void gemm_k(
    const __bf16* __restrict__ A, const __bf16* __restrict__ Bt,
    const float* __restrict__ bias, const __bf16* __restrict__ aux,
    const float* __restrict__ scal, void* __restrict__ out)
{
    constexpr int K = D_, N = D_;
    __shared__ __align__(16) __bf16 As[128][32];  // 8 KB
    __shared__ __align__(16) __bf16 Bs[64][32];   // 4 KB

    const int tid = threadIdx.x, wid = tid >> 6, lane = tid & 63;
    const int wr = wid >> 1, wc = wid & 1;          // 2x2 wave grid
    const int m0 = blockIdx.x * 128, n0 = blockIdx.y * 64;
    const int frow = lane & 15, kg8 = (lane >> 4) * 8;

    // staging linear offsets (bytes): A tile 8KB (2 issues/wave), B tile 4KB (1)
    const int la0 = (wid * 2 + 0) * 1024 + lane * 16;
    const int la1 = la0 + 1024;
    const int lb0 = wid * 1024 + lane * 16;
    const __bf16* Ag0 = A  + (size_t)(m0 + (la0 >> 6)) * K + ((la0 & 63) >> 1);
    const __bf16* Ag1 = A  + (size_t)(m0 + (la1 >> 6)) * K + ((la1 & 63) >> 1);
    const __bf16* Bg0 = Bt + (size_t)(n0 + (lb0 >> 6)) * K + ((lb0 & 63) >> 1);
    char* lAs = (char*)&As[0][0];
    char* lBs = (char*)&Bs[0][0];

    f32x4 acc[4][2] = {};

    for (int k0 = 0; k0 < K; k0 += 32) {
        async16(Ag0 + k0, lAs + la0);
        async16(Ag1 + k0, lAs + la1);
        async16(Bg0 + k0, lBs + lb0);
        __syncthreads();

        bf16x8 af[4], bfr[2];
#pragma unroll
        for (int m = 0; m < 4; ++m)
            af[m] = *(const bf16x8*)&As[wr * 64 + m * 16 + frow][kg8];
#pragma unroll
        for (int n = 0; n < 2; ++n)
            bfr[n] = *(const bf16x8*)&Bs[wc * 32 + n * 16 + frow][kg8];
#pragma unroll
        for (int m = 0; m < 4; ++m)
#pragma unroll
            for (int n = 0; n < 2; ++n)
                acc[m][n] = __builtin_amdgcn_mfma_f32_16x16x32_bf16(
                    af[m], bfr[n], acc[m][n], 0, 0, 0);
        __syncthreads();
    }

    const float s = (EPI >= 2) ? *scal : 0.f;
#pragma unroll
    for (int m = 0; m < 4; ++m) {
#pragma unroll
        for (int n = 0; n < 2; ++n) {
#pragma unroll
            for (int r = 0; r < 4; ++r) {
                const int row = m0 + wr * 64 + m * 16 + (lane >> 4) * 4 + r;
                const int col = n0 + wc * 32 + n * 16 + frow;
                const size_t idx = (size_t)row * N + col;
                float v = acc[m][n][r] + bias[col];
                if constexpr (EPI == 0) {
                    ((__bf16*)out)[idx] = (__bf16)v;
                } else if constexpr (EPI == 1) {
                    v = v > 0.f ? v : 0.2f * v;
                    ((__bf16*)out)[idx] = (__bf16)v;
                } else if constexpr (EPI == 2) {
                    ((__bf16*)out)[idx] = (__bf16)((float)aux[idx] + s * v);
                } else {
                    ((float*)out)[idx] = (float)aux[idx] + s * v;
                }
            }
        }
    }
}

// ---------------------------------------------------------------------------
// Fused attention (no softmax: elementwise sigmoid*tanh on logits).
// Block = (q-tile of 128, head, batch). 4 waves, each 32 q-rows.
// Per key-tile of 128: stage K [128key][64hd], Vt [64d][128key] in LDS;
// S = Q K^T (scaled), f = sigtanh(S), P (bf16) -> LDS, ctx += P V.
// ---------------------------------------------------------------------------
__global__ __launch_bounds__(256) void attn_k(
    const __bf16* __restrict__ Q, const __bf16* __restrict__ Kmat,
    const __bf16* __restrict__ VT, __bf16* __restrict__ CTX)
{
    __shared__ __align__(16) __bf16 Ks[128][64];   // 16 KB  [key][hd]
    __shared__ __align__(16) __bf16 Vs[64][128];   // 16 KB  [d][key]
    __shared__ __align__(16) __bf16 Ps[128][128];  // 32 KB  [q][key]

    const int tid = threadIdx.x, wid = tid >> 6, lane = tid & 63;
    const int qt = blockIdx.x, h = blockIdx.y, b = blockIdx.z;
    const int q0 = qt * 128;
    const int frow = lane & 15, kg8 = (lane >> 4) * 8;

    const __bf16* qbase = Q    + (size_t)(b * S_ + q0) * D_ + h * 64;
    const __bf16* kbase = Kmat + (size_t)b * S_ * D_ + h * 64;
    const __bf16* vbase = VT   + (size_t)(b * H_ + h) * 64 * S_;

    // preload q fragments: wave rows [wid*32, wid*32+32)
    bf16x8 qf[2][2];
#pragma unroll
    for (int m = 0; m < 2; ++m)
#pragma unroll
        for (int kk = 0; kk < 2; ++kk)
            qf[m][kk] = *(const bf16x8*)(qbase +
                (size_t)(wid * 32 + m * 16 + frow) * D_ + kk * 32 + kg8);

    f32x4 octx[2][4] = {};
    char* lKs = (char*)&Ks[0][0];
    char* lVs = (char*)&Vs[0][0];

    for (int kt = 0; kt < S_; kt += 128) {
        __syncthreads();  // all waves done reading Ks/Vs/Ps from prev iter
#pragma unroll
        for (int i = 0; i < 4; ++i) {
            const int o = (wid * 4 + i) * 1024 + lane * 16;  // 0..16KB
            async16(kbase + (size_t)(kt + (o >> 7)) * D_ + ((o & 127) >> 1), lKs + o);
            async16(vbase + (size_t)(o >> 8) * S_ + kt + ((o & 255) >> 1), lVs + o);
        }
        __syncthreads();  // staging complete

        // ---- S = Q K^T over hd (two 32-wide MFMA k-steps)
        f32x4 sacc[2][8] = {};
#pragma unroll
        for (int kk = 0; kk < 2; ++kk) {
            bf16x8 kf[8];
#pragma unroll
            for (int n = 0; n < 8; ++n)
                kf[n] = *(const bf16x8*)&Ks[n * 16 + frow][kk * 32 + kg8];
#pragma unroll
            for (int m = 0; m < 2; ++m)
#pragma unroll
                for (int n = 0; n < 8; ++n)
                    sacc[m][n] = __builtin_amdgcn_mfma_f32_16x16x32_bf16(
                        qf[m][kk], kf[n], sacc[m][n], 0, 0, 0);
        }
        // ---- activation, write P (bf16) to LDS
#pragma unroll
        for (int m = 0; m < 2; ++m)
#pragma unroll
            for (int n = 0; n < 8; ++n)
#pragma unroll
                for (int r = 0; r < 4; ++r) {
                    const float f = sigtanh(sacc[m][n][r] * 0.03125f);
                    Ps[wid * 32 + m * 16 + (lane >> 4) * 4 + r][n * 16 + frow] =
                        (__bf16)f;
                }
        __syncthreads();  // P ready

        // ---- ctx += P @ V  (reduction over 128 keys, 4 k-steps)
#pragma unroll
        for (int ks = 0; ks < 4; ++ks) {
            bf16x8 pf[2], vf[4];
#pragma unroll
            for (int m = 0; m < 2; ++m)
                pf[m] = *(const bf16x8*)&Ps[wid * 32 + m * 16 + frow][ks * 32 + kg8];
#pragma unroll
            for (int n = 0; n < 4; ++n)
                vf[n] = *(const bf16x8*)&Vs[n * 16 + frow][ks * 32 + kg8];
#pragma unroll
            for (int m = 0; m < 2; ++m)
#pragma unroll
                for (int n = 0; n < 4; ++n)
                    octx[m][n] = __builtin_amdgcn_mfma_f32_16x16x32_bf16(
                        pf[m], vf[n], octx[m][n], 0, 0, 0);
        }
    }

    // write ctx tile: CTX[b, q0+row, h*64+col] (layout [B,S,D])
#pragma unroll
    for (int m = 0; m < 2; ++m)
#pragma unroll
        for (int n = 0; n < 4; ++n)
#pragma unroll
            for (int r = 0; r < 4; ++r) {
                const int row = q0 + wid * 32 + m * 16 + (lane >> 4) * 4 + r;
                const int col = h * 64 + n * 16 + frow;
                CTX[(size_t)(b * S_ + row) * D_ + col] = (__bf16)octx[m][n][r];
            }
}

// ---------------------------------------------------------------------------
// Weight convert+transpose: W[k][n] f32 -> Wt[n][k] bf16 (7 weights batched).
// ---------------------------------------------------------------------------
struct WPack { const float* w[7]; };

__global__ __launch_bounds__(256) void conv_transpose_w(WPack p, __bf16* out) {
    __shared__ float t[32][33];
    const float* W = p.w[blockIdx.z];
    __bf16* o = out + (size_t)blockIdx.z * D_ * D_;
    const int c0 = blockIdx.x * 32, r0 = blockIdx.y * 32;
    const int tx = threadIdx.x, ty = threadIdx.y;
#pragma unroll
    for (int i = 0; i < 4; ++i)
        t[ty + i * 8][tx] = W[(size_t)(r0 + ty + i * 8) * D_ + c0 + tx];
    __syncthreads();
#pragma unroll
    for (int i = 0; i < 4; ++i)
        o[(size_t)(c0 + ty + i * 8) * D_ + r0 + tx] = (__bf16)t[tx][ty + i * 8];
}

// x f32 -> bf16 (vectorized)
__global__ __launch_bounds__(256) void conv_bf16(
    const float* __restrict__ in, __bf16* __restrict__ out, int n4)
{
    const int i = blockIdx.x * blockDim.x + threadIdx.x;
    if (i < n4) {
        f32x4 v = ((const f32x4*)in)[i];
        bf16x4 o;
        o[0] = (__bf16)v[0]; o[1] = (__bf16)v[1];
        o[2] = (__bf16)v[2]; o[3] = (__bf16)v[3];
        ((bf16x4*)out)[i] = o;
    }
}

// V [B*S][D] bf16 -> VT [(b*D + col)][S] bf16  (per-head transposed layout)
__global__ __launch_bounds__(256) void transpose_v(
    const __bf16* __restrict__ V, __bf16* __restrict__ VT)
{
    __shared__ __bf16 t[32][33];
    const int s0 = blockIdx.x * 32, c0 = blockIdx.y * 32, b = blockIdx.z;
    const int tx = threadIdx.x, ty = threadIdx.y;
#pragma unroll
    for (int i = 0; i < 4; ++i)
        t[ty + i * 8][tx] = V[(size_t)(b * S_ + s0 + ty + i * 8) * D_ + c0 + tx];
    __syncthreads();
#pragma unroll
    for (int i = 0; i < 4; ++i)
        VT[(size_t)(b * D_ + c0 + ty + i * 8) * S_ + s0 + tx] = t[tx][ty + i * 8];
}

// ---------------------------------------------------------------------------
extern "C" void kernel_launch(void* const* d_in, const int* in_sizes, int n_in,
                              void* d_out, int out_size, void* d_ws, size_t ws_size,
                              hipStream_t stream) {
    const float* x    = (const float*)d_in[0];
    const float* W_in = (const float*)d_in[1];
    const float* b_in = (const float*)d_in[2];
    const float* Wq   = (const float*)d_in[3];
    const float* bq   = (const float*)d_in[4];
    const float* Wk   = (const float*)d_in[5];
    const float* bk   = (const float*)d_in[6];
    const float* Wv   = (const float*)d_in[7];
    const float* bv   = (const float*)d_in[8];
    const float* Wo   = (const float*)d_in[9];
    const float* bo   = (const float*)d_in[10];
    const float* W1   = (const float*)d_in[11];
    const float* b1   = (const float*)d_in[12];
    const float* W2   = (const float*)d_in[13];
    const float* b2   = (const float*)d_in[14];
    const float* s_att = (const float*)d_in[15];
    const float* s_ff  = (const float*)d_in[16];

    char* ws = (char*)d_ws;
    const size_t WB = (size_t)D_ * D_ * 2;   // 2 MB per bf16 weight
    const size_t MB = (size_t)M_ * D_ * 2;   // 8 MB per bf16 activation
    __bf16* WT  = (__bf16*)(ws);
    __bf16* Hb  = (__bf16*)(ws + 7 * WB);
    __bf16* Qb  = (__bf16*)(ws + 7 * WB + 1 * MB);
    __bf16* Kb  = (__bf16*)(ws + 7 * WB + 2 * MB);
    __bf16* Vb  = (__bf16*)(ws + 7 * WB + 3 * MB);
    __bf16* VTb = (__bf16*)(ws + 7 * WB + 4 * MB);
    __bf16* Xb  = (__bf16*)(ws + 7 * WB + 5 * MB);
    // reuse dead buffers (x dead after gemm1; q,k dead after attention)
    __bf16* CTXb = Xb;
    __bf16* LATb = Qb;
    __bf16* FF1b = Kb;
    auto WTi = [&](int i) { return WT + (size_t)i * D_ * D_; };

    WPack wp;
    wp.w[0] = W_in; wp.w[1] = Wq; wp.w[2] = Wk; wp.w[3] = Wv;
    wp.w[4] = Wo;   wp.w[5] = W1; wp.w[6] = W2;
    conv_transpose_w<<<dim3(32, 32, 7), dim3(32, 8), 0, stream>>>(wp, WT);
    conv_bf16<<<dim3(4096), dim3(256), 0, stream>>>(x, Xb, (M_ * D_) / 4);

    const dim3 gg(32, 16), gb(256);
    // h = x @ W_in + b_in
    gemm_k<0><<<gg, gb, 0, stream>>>(Xb, WTi(0), b_in, nullptr, nullptr, Hb);
    // q,k,v projections
    gemm_k<0><<<gg, gb, 0, stream>>>(Hb, WTi(1), bq, nullptr, nullptr, Qb);
    gemm_k<0><<<gg, gb, 0, stream>>>(Hb, WTi(2), bk, nullptr, nullptr, Kb);
    gemm_k<0><<<gg, gb, 0, stream>>>(Hb, WTi(3), bv, nullptr, nullptr, Vb);
    transpose_v<<<dim3(64, 32, 2), dim3(32, 8), 0, stream>>>(Vb, VTb);
    // attention -> ctx
    attn_k<<<dim3(16, 16, 2), dim3(256), 0, stream>>>(Qb, Kb, VTb, CTXb);
    // latent = h + s_att * (ctx @ Wo + bo)
    gemm_k<2><<<gg, gb, 0, stream>>>(CTXb, WTi(4), bo, Hb, s_att, LATb);
    // ff1 = leaky_relu(latent @ W1 + b1)
    gemm_k<1><<<gg, gb, 0, stream>>>(LATb, WTi(5), b1, nullptr, nullptr, FF1b);
    // out = latent + s_ff * (ff1 @ W2 + b2)   (f32 output)
    gemm_k<3><<<gg, gb, 0, stream>>>(FF1b, WTi(6), b2, LATb, s_ff, d_out);
}

// Round 3
// 333.393 us; speedup vs baseline: 1.1577x; 1.1577x over previous
//
#include <hip/hip_runtime.h>
#include <cstdint>
#include <cstddef>

// ---------------------------------------------------------------------------
// TransformerLayer forward on MI355X (gfx950), bf16 MFMA pipeline.
// B=2, S=2048, D=1024, H=16, HD=64.  M = B*S = 4096 rows.
// Round 1: XOR-swizzled LDS (T2) in attention + BK=64 swizzled GEMM,
// fused QKV projection, cheaper activation, one fewer barrier per k-tile.
// Round 2: identical resubmit (round-1 bench was an infra failure).
// ---------------------------------------------------------------------------

#define B_ 2
#define S_ 2048
#define D_ 1024
#define H_ 16
#define M_ 4096

typedef __attribute__((ext_vector_type(4))) float  f32x4;
typedef __attribute__((ext_vector_type(8))) __bf16 bf16x8;
typedef __attribute__((ext_vector_type(4))) __bf16 bf16x4;

__device__ __forceinline__ void async16(const void* g, void* l) {
    __builtin_amdgcn_global_load_lds(
        (__attribute__((address_space(1))) void*)(g),
        (__attribute__((address_space(3))) void*)(l), 16, 0, 0);
}

// sigmoid(z)*tanh(z) == (1-u)/(1+u^2), u = exp(-z), z = s/32.
// u = exp2(s * -log2(e)/32); clamp exponent to avoid inf/inf.
__device__ __forceinline__ float actf(float s) {
    float t = fminf(s * -0.045084223f, 21.6f);
    float u = __builtin_amdgcn_exp2f(t);
    return (1.f - u) * __builtin_amdgcn_rcpf(1.f + u * u);
}

// ---------------------------------------------------------------------------
// GEMM: C[M][Ntot] = epilogue(A[M][1024] @ Bt[Ntot][1024]^T + bias)
// Tile BM x 128, BK=64, 4 waves (2x2), per wave (BM/2) x 64.
// LDS XOR-swizzled (row&7)<<4 on byte addr; staging via pre-swizzled
// global source + linear global_load_lds dest (both-sides rule).
// EPI: 0 bias->bf16 | 1 leaky(0.2)->bf16 | 2 aux+s*(.)->bf16 | 3 aux+s*(.)->f32
// ---------------------------------------------------------------------------
template <int BM, int EPI>
__global__ __launch_bounds__(256) void gemm_k(
    const __bf16* __restrict__ A, const __bf16* __restrict__ Bt,
    const float* __restrict__ bias, const __bf16* __restrict__ aux,
    const float* __restrict__ scal, void* __restrict__ out, int Ntot)
{
    constexpr int K = D_;
    constexpr int MF = BM / 32;     // m-fragments per wave
    __shared__ __align__(16) __bf16 As[BM][64];
    __shared__ __align__(16) __bf16 Bs[128][64];

    const int tid = threadIdx.x, wid = tid >> 6, lane = tid & 63;
    const int wr = wid >> 1, wc = wid & 1;
    const int m0 = blockIdx.x * BM, n0 = blockIdx.y * 128;
    const int frow = lane & 15;
    const int kb = (lane >> 4) * 16;   // k-group byte offset within 64B half-row
    char* lAs = (char*)As; char* lBs = (char*)Bs;

    f32x4 acc[MF][4] = {};

    for (int k0 = 0; k0 < K; k0 += 64) {
#pragma unroll
        for (int i = 0; i < MF; ++i) {           // A: BM*128B, MF issues/thread
            const int o = tid * 16 + i * 4096;
            const int row = o >> 7;
            const int cb = (o & 127) ^ ((row & 7) << 4);
            async16(A + (size_t)(m0 + row) * K + k0 + (cb >> 1), lAs + o);
        }
#pragma unroll
        for (int i = 0; i < 4; ++i) {            // B: 16KB, 4 issues/thread
            const int o = tid * 16 + i * 4096;
            const int row = o >> 7;
            const int cb = (o & 127) ^ ((row & 7) << 4);
            async16(Bt + (size_t)(n0 + row) * K + k0 + (cb >> 1), lBs + o);
        }
        __syncthreads();

#pragma unroll
        for (int kk = 0; kk < 2; ++kk) {
            bf16x8 af[MF], bfr[4];
#pragma unroll
            for (int m = 0; m < MF; ++m) {
                const int r = wr * (BM / 2) + m * 16 + frow;
                af[m] = *(const bf16x8*)(lAs + ((r * 128 + kk * 64 + kb) ^ ((r & 7) << 4)));
            }
#pragma unroll
            for (int n = 0; n < 4; ++n) {
                const int r = wc * 64 + n * 16 + frow;
                bfr[n] = *(const bf16x8*)(lBs + ((r * 128 + kk * 64 + kb) ^ ((r & 7) << 4)));
            }
#pragma unroll
            for (int m = 0; m < MF; ++m)
#pragma unroll
                for (int n = 0; n < 4; ++n)
                    acc[m][n] = __builtin_amdgcn_mfma_f32_16x16x32_bf16(
                        af[m], bfr[n], acc[m][n], 0, 0, 0);
        }
        __syncthreads();
    }

    const float sv = (EPI >= 2) ? *scal : 0.f;
#pragma unroll
    for (int m = 0; m < MF; ++m) {
#pragma unroll
        for (int n = 0; n < 4; ++n) {
#pragma unroll
            for (int r = 0; r < 4; ++r) {
                const int row = m0 + wr * (BM / 2) + m * 16 + (lane >> 4) * 4 + r;
                const int col = n0 + wc * 64 + n * 16 + frow;
                const size_t idx = (size_t)row * Ntot + col;
                float v = acc[m][n][r] + bias[col];
                if constexpr (EPI == 0) {
                    ((__bf16*)out)[idx] = (__bf16)v;
                } else if constexpr (EPI == 1) {
                    v = v > 0.f ? v : 0.2f * v;
                    ((__bf16*)out)[idx] = (__bf16)v;
                } else if constexpr (EPI == 2) {
                    ((__bf16*)out)[idx] = (__bf16)((float)aux[idx] + sv * v);
                } else {
                    ((float*)out)[idx] = (float)aux[idx] + sv * v;
                }
            }
        }
    }
}

// ---------------------------------------------------------------------------
// Fused attention (elementwise sigmoid*tanh on logits — no softmax).
// Block = (q-tile 128, head, batch). 4 waves, each 32 q-rows.
// All LDS tiles XOR-swizzled: byte ^= (row&7)<<4.
// Ps is wave-private per 32-row stripe -> no barrier between P write and PV.
// ---------------------------------------------------------------------------
__global__ __launch_bounds__(256) void attn_k(
    const __bf16* __restrict__ Q, const __bf16* __restrict__ Kmat,
    const __bf16* __restrict__ VT, __bf16* __restrict__ CTX, int ld)
{
    __shared__ __align__(16) __bf16 Ks[128][64];   // 16 KB [key][hd]
    __shared__ __align__(16) __bf16 Vs[64][128];   // 16 KB [d][key]
    __shared__ __align__(16) __bf16 Ps[128][128];  // 32 KB [q][key]

    const int tid = threadIdx.x, wid = tid >> 6, lane = tid & 63;
    const int qt = blockIdx.x, h = blockIdx.y, b = blockIdx.z;
    const int q0 = qt * 128;
    const int frow = lane & 15, kg8 = (lane >> 4) * 8;
    const int kb = kg8 * 2;

    const __bf16* qbase = Q    + (size_t)(b * S_ + q0) * ld + h * 64;
    const __bf16* kbase = Kmat + (size_t)b * S_ * ld + h * 64;
    const __bf16* vbase = VT   + (size_t)(b * H_ + h) * 64 * S_;

    bf16x8 qf[2][2];
#pragma unroll
    for (int m = 0; m < 2; ++m)
#pragma unroll
        for (int kk = 0; kk < 2; ++kk)
            qf[m][kk] = *(const bf16x8*)(qbase +
                (size_t)(wid * 32 + m * 16 + frow) * ld + kk * 32 + kg8);

    f32x4 octx[2][4] = {};
    char* lKs = (char*)Ks; char* lVs = (char*)Vs; char* lPs = (char*)Ps;

    for (int kt = 0; kt < S_; kt += 128) {
        __syncthreads();  // all waves done reading Ks/Vs from prev iter
#pragma unroll
        for (int i = 0; i < 4; ++i) {
            const int o = (wid * 4 + i) * 1024 + lane * 16;   // 0..16KB
            {   // K: row=key (128B rows), pre-swizzled source column
                const int row = o >> 7;
                const int cb = (o & 127) ^ ((row & 7) << 4);
                async16(kbase + (size_t)(kt + row) * ld + (cb >> 1), lKs + o);
            }
            {   // V^T: row=d (256B rows)
                const int row = o >> 8;
                const int cb = (o & 255) ^ ((row & 7) << 4);
                async16(vbase + (size_t)row * S_ + kt + (cb >> 1), lVs + o);
            }
        }
        __syncthreads();  // staging complete

        // ---- S = Q K^T (scaled inside actf)
        f32x4 sacc[2][8] = {};
#pragma unroll
        for (int kk = 0; kk < 2; ++kk) {
            bf16x8 kf[8];
#pragma unroll
            for (int n = 0; n < 8; ++n) {
                const int r = n * 16 + frow;
                kf[n] = *(const bf16x8*)(lKs + ((r * 128 + kk * 64 + kb) ^ ((r & 7) << 4)));
            }
#pragma unroll
            for (int m = 0; m < 2; ++m)
#pragma unroll
                for (int n = 0; n < 8; ++n)
                    sacc[m][n] = __builtin_amdgcn_mfma_f32_16x16x32_bf16(
                        qf[m][kk], kf[n], sacc[m][n], 0, 0, 0);
        }

        // ---- activation -> P (bf16, swizzled LDS, wave-private rows)
#pragma unroll
        for (int m = 0; m < 2; ++m)
#pragma unroll
            for (int n = 0; n < 8; ++n)
#pragma unroll
                for (int r = 0; r < 4; ++r) {
                    const float f = actf(sacc[m][n][r]);
                    const int qr = wid * 32 + m * 16 + (lane >> 4) * 4 + r;
                    const int byte = qr * 256 + (n * 16 + frow) * 2;
                    *(__bf16*)(lPs + (byte ^ ((qr & 7) << 4))) = (__bf16)f;
                }

        // ---- ctx += P @ V  (wave-local P rows: no barrier needed)
#pragma unroll
        for (int ks = 0; ks < 4; ++ks) {
            bf16x8 pf[2], vf[4];
#pragma unroll
            for (int m = 0; m < 2; ++m) {
                const int r = wid * 32 + m * 16 + frow;
                pf[m] = *(const bf16x8*)(lPs + ((r * 256 + ks * 64 + kb) ^ ((r & 7) << 4)));
            }
#pragma unroll
            for (int n = 0; n < 4; ++n) {
                const int r = n * 16 + frow;
                vf[n] = *(const bf16x8*)(lVs + ((r * 256 + ks * 64 + kb) ^ ((r & 7) << 4)));
            }
#pragma unroll
            for (int m = 0; m < 2; ++m)
#pragma unroll
                for (int n = 0; n < 4; ++n)
                    octx[m][n] = __builtin_amdgcn_mfma_f32_16x16x32_bf16(
                        pf[m], vf[n], octx[m][n], 0, 0, 0);
        }
    }

#pragma unroll
    for (int m = 0; m < 2; ++m)
#pragma unroll
        for (int n = 0; n < 4; ++n)
#pragma unroll
            for (int r = 0; r < 4; ++r) {
                const int row = q0 + wid * 32 + m * 16 + (lane >> 4) * 4 + r;
                const int col = h * 64 + n * 16 + frow;
                CTX[(size_t)(b * S_ + row) * D_ + col] = (__bf16)octx[m][n][r];
            }
}

// ---------------------------------------------------------------------------
struct WPack { const float* w[7]; };

__global__ __launch_bounds__(256) void conv_transpose_w(WPack p, __bf16* out) {
    __shared__ float t[32][33];
    const float* W = p.w[blockIdx.z];
    __bf16* o = out + (size_t)blockIdx.z * D_ * D_;
    const int c0 = blockIdx.x * 32, r0 = blockIdx.y * 32;
    const int tx = threadIdx.x, ty = threadIdx.y;
#pragma unroll
    for (int i = 0; i < 4; ++i)
        t[ty + i * 8][tx] = W[(size_t)(r0 + ty + i * 8) * D_ + c0 + tx];
    __syncthreads();
#pragma unroll
    for (int i = 0; i < 4; ++i)
        o[(size_t)(c0 + ty + i * 8) * D_ + r0 + tx] = (__bf16)t[tx][ty + i * 8];
}

__global__ __launch_bounds__(256) void conv_bf16(
    const float* __restrict__ in, __bf16* __restrict__ out, int n4)
{
    const int i = blockIdx.x * blockDim.x + threadIdx.x;
    if (i < n4) {
        f32x4 v = ((const f32x4*)in)[i];
        bf16x4 o;
        o[0] = (__bf16)v[0]; o[1] = (__bf16)v[1];
        o[2] = (__bf16)v[2]; o[3] = (__bf16)v[3];
        ((bf16x4*)out)[i] = o;
    }
}

__global__ __launch_bounds__(256) void bcat_k(
    const float* __restrict__ bq, const float* __restrict__ bk,
    const float* __restrict__ bv, float* __restrict__ o)
{
    const int i = blockIdx.x * 256 + threadIdx.x;   // 0..3071
    o[i] = i < 1024 ? bq[i] : (i < 2048 ? bk[i - 1024] : bv[i - 2048]);
}

// V rows of QKV [B*S][ld] -> VT[(b*D + col)][S]
__global__ __launch_bounds__(256) void transpose_v(
    const __bf16* __restrict__ V, __bf16* __restrict__ VT, int ld)
{
    __shared__ __bf16 t[32][33];
    const int s0 = blockIdx.x * 32, c0 = blockIdx.y * 32, b = blockIdx.z;
    const int tx = threadIdx.x, ty = threadIdx.y;
#pragma unroll
    for (int i = 0; i < 4; ++i)
        t[ty + i * 8][tx] = V[(size_t)(b * S_ + s0 + ty + i * 8) * ld + c0 + tx];
    __syncthreads();
#pragma unroll
    for (int i = 0; i < 4; ++i)
        VT[(size_t)(b * D_ + c0 + ty + i * 8) * S_ + s0 + tx] = t[tx][ty + i * 8];
}

// ---------------------------------------------------------------------------
extern "C" void kernel_launch(void* const* d_in, const int* in_sizes, int n_in,
                              void* d_out, int out_size, void* d_ws, size_t ws_size,
                              hipStream_t stream) {
    const float* x    = (const float*)d_in[0];
    const float* W_in = (const float*)d_in[1];
    const float* b_in = (const float*)d_in[2];
    const float* Wq   = (const float*)d_in[3];
    const float* bq   = (const float*)d_in[4];
    const float* Wk   = (const float*)d_in[5];
    const float* bk   = (const float*)d_in[6];
    const float* Wv   = (const float*)d_in[7];
    const float* bv   = (const float*)d_in[8];
    const float* Wo   = (const float*)d_in[9];
    const float* bo   = (const float*)d_in[10];
    const float* W1   = (const float*)d_in[11];
    const float* b1   = (const float*)d_in[12];
    const float* W2   = (const float*)d_in[13];
    const float* b2   = (const float*)d_in[14];
    const float* s_att = (const float*)d_in[15];
    const float* s_ff  = (const float*)d_in[16];

    char* ws = (char*)d_ws;
    const size_t WB = (size_t)D_ * D_ * 2;       // 2 MB / bf16 weight
    const size_t MB = (size_t)M_ * D_ * 2;       // 8 MB / bf16 activation
    __bf16* WT   = (__bf16*)(ws);                           // 14 MB
    __bf16* Hb   = (__bf16*)(ws + 7 * WB);                  // 8 MB
    __bf16* QKVb = (__bf16*)(ws + 7 * WB + MB);             // 24 MB
    __bf16* VTb  = (__bf16*)(ws + 7 * WB + 4 * MB);         // 8 MB
    __bf16* Xb   = (__bf16*)(ws + 7 * WB + 5 * MB);         // 8 MB
    float*  bcat = (float*)VTb;       // alias: bcat dead before VTb written
    __bf16* CTXb = Xb;                // x dead after first GEMM
    __bf16* LATb = QKVb;              // qkv dead after attention
    __bf16* FF1b = QKVb + (size_t)M_ * D_;
    auto WTi = [&](int i) { return WT + (size_t)i * D_ * D_; };

    WPack wp;
    wp.w[0] = W_in; wp.w[1] = Wq; wp.w[2] = Wk; wp.w[3] = Wv;
    wp.w[4] = Wo;   wp.w[5] = W1; wp.w[6] = W2;
    conv_transpose_w<<<dim3(32, 32, 7), dim3(32, 8), 0, stream>>>(wp, WT);
    conv_bf16<<<dim3(4096), dim3(256), 0, stream>>>(x, Xb, (M_ * D_) / 4);
    bcat_k<<<dim3(12), dim3(256), 0, stream>>>(bq, bk, bv, bcat);

    // h = x @ W_in + b_in
    gemm_k<64, 0><<<dim3(64, 8), dim3(256), 0, stream>>>(
        Xb, WTi(0), b_in, nullptr, nullptr, Hb, D_);
    // qkv = h @ [Wq|Wk|Wv] + bcat   (fused, N=3072)
    gemm_k<128, 0><<<dim3(32, 24), dim3(256), 0, stream>>>(
        Hb, WTi(1), bcat, nullptr, nullptr, QKVb, 3 * D_);
    transpose_v<<<dim3(64, 32, 2), dim3(32, 8), 0, stream>>>(
        QKVb + 2 * D_, VTb, 3 * D_);
    attn_k<<<dim3(16, 16, 2), dim3(256), 0, stream>>>(
        QKVb, QKVb + D_, VTb, CTXb, 3 * D_);
    // latent = h + s_att * (ctx @ Wo + bo)
    gemm_k<64, 2><<<dim3(64, 8), dim3(256), 0, stream>>>(
        CTXb, WTi(4), bo, Hb, s_att, LATb, D_);
    // ff1 = leaky_relu(latent @ W1 + b1)
    gemm_k<64, 1><<<dim3(64, 8), dim3(256), 0, stream>>>(
        LATb, WTi(5), b1, nullptr, nullptr, FF1b, D_);
    // out = latent + s_ff * (ff1 @ W2 + b2)  (f32)
    gemm_k<64, 3><<<dim3(64, 8), dim3(256), 0, stream>>>(
        FF1b, WTi(6), b2, LATb, s_ff, d_out, D_);
}

// Round 5
// 298.992 us; speedup vs baseline: 1.2909x; 1.1151x over previous
//
#include <hip/hip_runtime.h>
#include <cstdint>
#include <cstddef>

// ---------------------------------------------------------------------------
// TransformerLayer forward on MI355X (gfx950), bf16 MFMA pipeline.
// B=2, S=2048, D=1024, H=16, HD=64.  M = B*S = 4096 rows.
// Round 4: attention occupancy rework (q-tile 64, KV dbuf, swapped QK^T with
// packed b64 P-writes, launch_bounds(256,4) -> 4 blocks/CU) + GEMM 2-phase
// double-buffer (stage(next) before compute(cur), 1 barrier per K-step).
// Round 5: identical resubmit (round-4 bench was a GPU-acquisition timeout).
// ---------------------------------------------------------------------------

#define B_ 2
#define S_ 2048
#define D_ 1024
#define H_ 16
#define M_ 4096

typedef __attribute__((ext_vector_type(4))) float  f32x4;
typedef __attribute__((ext_vector_type(8))) __bf16 bf16x8;
typedef __attribute__((ext_vector_type(4))) __bf16 bf16x4;

__device__ __forceinline__ void async16(const void* g, void* l) {
    __builtin_amdgcn_global_load_lds(
        (__attribute__((address_space(1))) void*)(g),
        (__attribute__((address_space(3))) void*)(l), 16, 0, 0);
}

// sigmoid(z)*tanh(z) == (1-u)/(1+u^2), u = exp(-z), z = s/32.
// u = exp2(s * -log2(e)/32); clamp exponent to avoid inf/inf.
__device__ __forceinline__ float actf(float s) {
    float t = fminf(s * -0.045084223f, 21.6f);
    float u = __builtin_amdgcn_exp2f(t);
    return (1.f - u) * __builtin_amdgcn_rcpf(1.f + u * u);
}

// ---------------------------------------------------------------------------
// GEMM: C[M][Ntot] = epilogue(A[M][1024] @ Bt[Ntot][1024]^T + bias)
// Tile BM x 128, BK=64, 4 waves (2x2), per wave (BM/2) x 64.
// Double-buffered LDS, 2-phase: stage(next) issued before compute(cur);
// the barrier's implicit vmcnt(0)+lgkmcnt(0) drain provides ordering.
// LDS XOR-swizzled (row&7)<<4 on byte addr (pre-swizzled global source).
// EPI: 0 bias->bf16 | 1 leaky(0.2)->bf16 | 2 aux+s*(.)->bf16 | 3 aux+s*(.)->f32
// ---------------------------------------------------------------------------
template <int BM, int EPI>
__global__ __launch_bounds__(256) void gemm_k(
    const __bf16* __restrict__ A, const __bf16* __restrict__ Bt,
    const float* __restrict__ bias, const __bf16* __restrict__ aux,
    const float* __restrict__ scal, void* __restrict__ out, int Ntot)
{
    constexpr int K = D_;
    constexpr int MF = BM / 32;     // m-fragments per wave
    __shared__ __align__(16) __bf16 As[2][BM][64];
    __shared__ __align__(16) __bf16 Bs[2][128][64];

    const int tid = threadIdx.x, wid = tid >> 6, lane = tid & 63;
    const int wr = wid >> 1, wc = wid & 1;
    const int m0 = blockIdx.x * BM, n0 = blockIdx.y * 128;
    const int frow = lane & 15;
    const int kb = (lane >> 4) * 16;   // k-group byte offset within 128B row
    char* cAs = (char*)As; char* cBs = (char*)Bs;

    f32x4 acc[MF][4] = {};

    auto stage = [&](int buf, int k0) {
        char* lA = cAs + buf * (BM * 128);
        char* lB = cBs + buf * (128 * 128);
#pragma unroll
        for (int i = 0; i < MF; ++i) {           // A tile: BM*128B
            const int o = tid * 16 + i * 4096;
            const int row = o >> 7;
            const int cb = (o & 127) ^ ((row & 7) << 4);
            async16(A + (size_t)(m0 + row) * K + k0 + (cb >> 1), lA + o);
        }
#pragma unroll
        for (int i = 0; i < 4; ++i) {            // B tile: 16KB
            const int o = tid * 16 + i * 4096;
            const int row = o >> 7;
            const int cb = (o & 127) ^ ((row & 7) << 4);
            async16(Bt + (size_t)(n0 + row) * K + k0 + (cb >> 1), lB + o);
        }
    };

    stage(0, 0);
    __syncthreads();                 // drains vmcnt: buf0 ready
    int cur = 0;

    for (int k0 = 0; k0 < K; k0 += 64) {
        if (k0 + 64 < K) stage(cur ^ 1, k0 + 64);   // overlap with compute
        char* lA = cAs + cur * (BM * 128);
        char* lB = cBs + cur * (128 * 128);
#pragma unroll
        for (int kk = 0; kk < 2; ++kk) {
            bf16x8 af[MF], bfr[4];
#pragma unroll
            for (int m = 0; m < MF; ++m) {
                const int r = wr * (BM / 2) + m * 16 + frow;
                af[m] = *(const bf16x8*)(lA + ((r * 128 + kk * 64 + kb) ^ ((r & 7) << 4)));
            }
#pragma unroll
            for (int n = 0; n < 4; ++n) {
                const int r = wc * 64 + n * 16 + frow;
                bfr[n] = *(const bf16x8*)(lB + ((r * 128 + kk * 64 + kb) ^ ((r & 7) << 4)));
            }
#pragma unroll
            for (int m = 0; m < MF; ++m)
#pragma unroll
                for (int n = 0; n < 4; ++n)
                    acc[m][n] = __builtin_amdgcn_mfma_f32_16x16x32_bf16(
                        af[m], bfr[n], acc[m][n], 0, 0, 0);
        }
        __syncthreads();             // next buf staged + this buf's reads done
        cur ^= 1;
    }

    const float sv = (EPI >= 2) ? *scal : 0.f;
#pragma unroll
    for (int m = 0; m < MF; ++m) {
#pragma unroll
        for (int n = 0; n < 4; ++n) {
#pragma unroll
            for (int r = 0; r < 4; ++r) {
                const int row = m0 + wr * (BM / 2) + m * 16 + (lane >> 4) * 4 + r;
                const int col = n0 + wc * 64 + n * 16 + frow;
                const size_t idx = (size_t)row * Ntot + col;
                float v = acc[m][n][r] + bias[col];
                if constexpr (EPI == 0) {
                    ((__bf16*)out)[idx] = (__bf16)v;
                } else if constexpr (EPI == 1) {
                    v = v > 0.f ? v : 0.2f * v;
                    ((__bf16*)out)[idx] = (__bf16)v;
                } else if constexpr (EPI == 2) {
                    ((__bf16*)out)[idx] = (__bf16)((float)aux[idx] + sv * v);
                } else {
                    ((float*)out)[idx] = (float)aux[idx] + sv * v;
                }
            }
        }
    }
}

// ---------------------------------------------------------------------------
// Fused attention (elementwise sigmoid*tanh on logits — no softmax).
// Block = (q-tile 64, head, batch). 4 waves x 16 q-rows. KVBLK=64.
// K/V double-buffered (1 barrier/tile). Swapped QK^T: scc = mfma(K,Q) gives
// lane 4 consecutive keys for one q -> activation packs to bf16x4 ->
// single ds_write_b64 per 16 keys. Ps wave-private (no P barrier).
// All LDS XOR-swizzled: byte ^= (row&7)<<4. LDS 40KB, VGPR<=128 -> 4 blk/CU.
// ---------------------------------------------------------------------------
__global__ __launch_bounds__(256, 4) void attn_k(
    const __bf16* __restrict__ Q, const __bf16* __restrict__ Kmat,
    const __bf16* __restrict__ VT, __bf16* __restrict__ CTX, int ld)
{
    __shared__ __align__(16) __bf16 Ks[2][64][64];  // 16 KB [buf][key][hd]
    __shared__ __align__(16) __bf16 Vs[2][64][64];  // 16 KB [buf][d][key]
    __shared__ __align__(16) __bf16 Ps[64][64];     //  8 KB [q][key]

    const int tid = threadIdx.x, wid = tid >> 6, lane = tid & 63;
    const int qt = blockIdx.x, h = blockIdx.y, b = blockIdx.z;
    const int q0 = qt * 64;
    const int frow = lane & 15, g = lane >> 4;
    const int kg8 = g * 8, kb = g * 16;
    const int qrow = wid * 16 + frow;          // this lane's q row (local)

    const __bf16* qbase = Q    + (size_t)(b * S_ + q0) * ld + h * 64;
    const __bf16* kbase = Kmat + (size_t)b * S_ * ld + h * 64;
    const __bf16* vbase = VT   + (size_t)(b * H_ + h) * 64 * S_;

    bf16x8 qf[2];
#pragma unroll
    for (int kk = 0; kk < 2; ++kk)
        qf[kk] = *(const bf16x8*)(qbase + (size_t)qrow * ld + kk * 32 + kg8);

    f32x4 octx[4] = {};
    char* cKs = (char*)Ks; char* cVs = (char*)Vs; char* lPs = (char*)Ps;

    auto stageKV = [&](int buf, int kt) {
#pragma unroll
        for (int i = 0; i < 2; ++i) {
            const int o = tid * 16 + i * 4096;           // 0..8KB
            const int row = o >> 7;
            const int cb = (o & 127) ^ ((row & 7) << 4);
            async16(kbase + (size_t)(kt + row) * ld + (cb >> 1),
                    cKs + buf * 8192 + o);
            async16(vbase + (size_t)row * S_ + kt + (cb >> 1),
                    cVs + buf * 8192 + o);
        }
    };

    stageKV(0, 0);
    __syncthreads();
    int cur = 0;

    for (int kt = 0; kt < S_; kt += 64) {
        if (kt + 64 < S_) stageKV(cur ^ 1, kt + 64);
        char* lKs = cKs + cur * 8192;
        char* lVs = cVs + cur * 8192;

        // ---- S^T = K Q^T: lane holds P[key=16n+4g+r][q=qrow]
        f32x4 scc[4] = {};
#pragma unroll
        for (int kk = 0; kk < 2; ++kk) {
            bf16x8 kf[4];
#pragma unroll
            for (int n = 0; n < 4; ++n) {
                const int r = n * 16 + frow;
                kf[n] = *(const bf16x8*)(lKs + ((r * 128 + kk * 64 + kb) ^ ((r & 7) << 4)));
            }
#pragma unroll
            for (int n = 0; n < 4; ++n)
                scc[n] = __builtin_amdgcn_mfma_f32_16x16x32_bf16(
                    kf[n], qf[kk], scc[n], 0, 0, 0);
        }

        // ---- activation + packed b64 P-write (4 consecutive keys per write)
#pragma unroll
        for (int n = 0; n < 4; ++n) {
            bf16x4 pw;
#pragma unroll
            for (int r = 0; r < 4; ++r) pw[r] = (__bf16)actf(scc[n][r]);
            *(bf16x4*)(lPs + ((qrow * 128 + n * 32 + g * 8) ^ ((qrow & 7) << 4))) = pw;
        }

        // ---- ctx += P @ V  (wave-private P rows: no barrier)
#pragma unroll
        for (int ks = 0; ks < 2; ++ks) {
            bf16x8 pf = *(const bf16x8*)(lPs +
                ((qrow * 128 + ks * 64 + kb) ^ ((qrow & 7) << 4)));
            bf16x8 vf[4];
#pragma unroll
            for (int nd = 0; nd < 4; ++nd) {
                const int rd = nd * 16 + frow;
                vf[nd] = *(const bf16x8*)(lVs + ((rd * 128 + ks * 64 + kb) ^ ((rd & 7) << 4)));
            }
#pragma unroll
            for (int nd = 0; nd < 4; ++nd)
                octx[nd] = __builtin_amdgcn_mfma_f32_16x16x32_bf16(
                    pf, vf[nd], octx[nd], 0, 0, 0);
        }
        __syncthreads();             // next K/V staged; this buf's reads done
        cur ^= 1;
    }

#pragma unroll
    for (int nd = 0; nd < 4; ++nd)
#pragma unroll
        for (int r = 0; r < 4; ++r) {
            const int row = q0 + wid * 16 + g * 4 + r;
            const int col = h * 64 + nd * 16 + frow;
            CTX[(size_t)(b * S_ + row) * D_ + col] = (__bf16)octx[nd][r];
        }
}

// ---------------------------------------------------------------------------
struct WPack { const float* w[7]; };

__global__ __launch_bounds__(256) void conv_transpose_w(WPack p, __bf16* out) {
    __shared__ float t[32][33];
    const float* W = p.w[blockIdx.z];
    __bf16* o = out + (size_t)blockIdx.z * D_ * D_;
    const int c0 = blockIdx.x * 32, r0 = blockIdx.y * 32;
    const int tx = threadIdx.x, ty = threadIdx.y;
#pragma unroll
    for (int i = 0; i < 4; ++i)
        t[ty + i * 8][tx] = W[(size_t)(r0 + ty + i * 8) * D_ + c0 + tx];
    __syncthreads();
#pragma unroll
    for (int i = 0; i < 4; ++i)
        o[(size_t)(c0 + ty + i * 8) * D_ + r0 + tx] = (__bf16)t[tx][ty + i * 8];
}

__global__ __launch_bounds__(256) void conv_bf16(
    const float* __restrict__ in, __bf16* __restrict__ out, int n4)
{
    const int i = blockIdx.x * blockDim.x + threadIdx.x;
    if (i < n4) {
        f32x4 v = ((const f32x4*)in)[i];
        bf16x4 o;
        o[0] = (__bf16)v[0]; o[1] = (__bf16)v[1];
        o[2] = (__bf16)v[2]; o[3] = (__bf16)v[3];
        ((bf16x4*)out)[i] = o;
    }
}

__global__ __launch_bounds__(256) void bcat_k(
    const float* __restrict__ bq, const float* __restrict__ bk,
    const float* __restrict__ bv, float* __restrict__ o)
{
    const int i = blockIdx.x * 256 + threadIdx.x;   // 0..3071
    o[i] = i < 1024 ? bq[i] : (i < 2048 ? bk[i - 1024] : bv[i - 2048]);
}

// V rows of QKV [B*S][ld] -> VT[(b*D + col)][S]
__global__ __launch_bounds__(256) void transpose_v(
    const __bf16* __restrict__ V, __bf16* __restrict__ VT, int ld)
{
    __shared__ __bf16 t[32][33];
    const int s0 = blockIdx.x * 32, c0 = blockIdx.y * 32, b = blockIdx.z;
    const int tx = threadIdx.x, ty = threadIdx.y;
#pragma unroll
    for (int i = 0; i < 4; ++i)
        t[ty + i * 8][tx] = V[(size_t)(b * S_ + s0 + ty + i * 8) * ld + c0 + tx];
    __syncthreads();
#pragma unroll
    for (int i = 0; i < 4; ++i)
        VT[(size_t)(b * D_ + c0 + ty + i * 8) * S_ + s0 + tx] = t[tx][ty + i * 8];
}

// ---------------------------------------------------------------------------
extern "C" void kernel_launch(void* const* d_in, const int* in_sizes, int n_in,
                              void* d_out, int out_size, void* d_ws, size_t ws_size,
                              hipStream_t stream) {
    const float* x    = (const float*)d_in[0];
    const float* W_in = (const float*)d_in[1];
    const float* b_in = (const float*)d_in[2];
    const float* Wq   = (const float*)d_in[3];
    const float* bq   = (const float*)d_in[4];
    const float* Wk   = (const float*)d_in[5];
    const float* bk   = (const float*)d_in[6];
    const float* Wv   = (const float*)d_in[7];
    const float* bv   = (const float*)d_in[8];
    const float* Wo   = (const float*)d_in[9];
    const float* bo   = (const float*)d_in[10];
    const float* W1   = (const float*)d_in[11];
    const float* b1   = (const float*)d_in[12];
    const float* W2   = (const float*)d_in[13];
    const float* b2   = (const float*)d_in[14];
    const float* s_att = (const float*)d_in[15];
    const float* s_ff  = (const float*)d_in[16];

    char* ws = (char*)d_ws;
    const size_t WB = (size_t)D_ * D_ * 2;       // 2 MB / bf16 weight
    const size_t MB = (size_t)M_ * D_ * 2;       // 8 MB / bf16 activation
    __bf16* WT   = (__bf16*)(ws);                           // 14 MB
    __bf16* Hb   = (__bf16*)(ws + 7 * WB);                  // 8 MB
    __bf16* QKVb = (__bf16*)(ws + 7 * WB + MB);             // 24 MB
    __bf16* VTb  = (__bf16*)(ws + 7 * WB + 4 * MB);         // 8 MB
    __bf16* Xb   = (__bf16*)(ws + 7 * WB + 5 * MB);         // 8 MB
    float*  bcat = (float*)VTb;       // alias: bcat dead before VTb written
    __bf16* CTXb = Xb;                // x dead after first GEMM
    __bf16* LATb = QKVb;              // qkv dead after attention
    __bf16* FF1b = QKVb + (size_t)M_ * D_;
    auto WTi = [&](int i) { return WT + (size_t)i * D_ * D_; };

    WPack wp;
    wp.w[0] = W_in; wp.w[1] = Wq; wp.w[2] = Wk; wp.w[3] = Wv;
    wp.w[4] = Wo;   wp.w[5] = W1; wp.w[6] = W2;
    conv_transpose_w<<<dim3(32, 32, 7), dim3(32, 8), 0, stream>>>(wp, WT);
    conv_bf16<<<dim3(4096), dim3(256), 0, stream>>>(x, Xb, (M_ * D_) / 4);
    bcat_k<<<dim3(12), dim3(256), 0, stream>>>(bq, bk, bv, bcat);

    // h = x @ W_in + b_in
    gemm_k<64, 0><<<dim3(64, 8), dim3(256), 0, stream>>>(
        Xb, WTi(0), b_in, nullptr, nullptr, Hb, D_);
    // qkv = h @ [Wq|Wk|Wv] + bcat   (fused, N=3072)
    gemm_k<128, 0><<<dim3(32, 24), dim3(256), 0, stream>>>(
        Hb, WTi(1), bcat, nullptr, nullptr, QKVb, 3 * D_);
    transpose_v<<<dim3(64, 32, 2), dim3(32, 8), 0, stream>>>(
        QKVb + 2 * D_, VTb, 3 * D_);
    attn_k<<<dim3(32, 16, 2), dim3(256), 0, stream>>>(
        QKVb, QKVb + D_, VTb, CTXb, 3 * D_);
    // latent = h + s_att * (ctx @ Wo + bo)
    gemm_k<64, 2><<<dim3(64, 8), dim3(256), 0, stream>>>(
        CTXb, WTi(4), bo, Hb, s_att, LATb, D_);
    // ff1 = leaky_relu(latent @ W1 + b1)
    gemm_k<64, 1><<<dim3(64, 8), dim3(256), 0, stream>>>(
        LATb, WTi(5), b1, nullptr, nullptr, FF1b, D_);
    // out = latent + s_ff * (ff1 @ W2 + b2)  (f32)
    gemm_k<64, 3><<<dim3(64, 8), dim3(256), 0, stream>>>(
        FF1b, WTi(6), b2, LATb, s_ff, d_out, D_);
}

// Round 6
// 290.675 us; speedup vs baseline: 1.3279x; 1.0286x over previous
//
#include <hip/hip_runtime.h>
#include <cstdint>
#include <cstddef>

// ---------------------------------------------------------------------------
// TransformerLayer forward on MI355X (gfx950), bf16 MFMA pipeline.
// B=2, S=2048, D=1024, H=16, HD=64.  M = B*S = 4096 rows.
// Round 6: GEMM -> 128x128 tile, 4 waves x (64x64), counted-vmcnt dbuf
// (raw s_barrier + s_waitcnt vmcnt(8), never drain-to-0 in steady state).
// Attention -> XCD-bijective block swizzle, unroll-2 (compile-time LDS
// addrs), counted vmcnt staging, s_setprio(1) around MFMA clusters.
// ---------------------------------------------------------------------------

#define B_ 2
#define S_ 2048
#define D_ 1024
#define H_ 16
#define M_ 4096

typedef __attribute__((ext_vector_type(4))) float  f32x4;
typedef __attribute__((ext_vector_type(8))) __bf16 bf16x8;
typedef __attribute__((ext_vector_type(4))) __bf16 bf16x4;

#define WAITVM(N) asm volatile("s_waitcnt vmcnt(" #N ")" ::: "memory")

__device__ __forceinline__ void async16(const void* g, void* l) {
    __builtin_amdgcn_global_load_lds(
        (__attribute__((address_space(1))) void*)(g),
        (__attribute__((address_space(3))) void*)(l), 16, 0, 0);
}

// sigmoid(z)*tanh(z) == (1-u)/(1+u^2), u = exp(-z), z = s/32.
// u = exp2(s * -log2(e)/32); clamp exponent to avoid inf/inf.
__device__ __forceinline__ float actf(float s) {
    float t = fminf(s * -0.045084223f, 21.6f);
    float u = __builtin_amdgcn_exp2f(t);
    return (1.f - u) * __builtin_amdgcn_rcpf(1.f + u * u);
}

// ---------------------------------------------------------------------------
// GEMM: C[M][Ntot] = epilogue(A[M][1024] @ Bt[Ntot][1024]^T + bias)
// Tile 128x128, BK=64, 4 waves (2x2), each wave owns a 64x64 quadrant
// (acc 4x4) -> per K-step 32 MFMA : 16 ds_read_b128.
// Double-buffered LDS (64 KB) with counted vmcnt: stage issued right after
// the buffer is fully consumed (post-barrier), waited with vmcnt(8) one
// full compute phase later. No vmcnt(0) drain in steady state.
// LDS XOR-swizzled (row&7)<<4; pre-swizzled global source (both-sides rule).
// M is fixed at 4096 -> 32 m-tiles; XCD-bijective swizzle on 1D grid.
// EPI: 0 bias->bf16 | 1 leaky(0.2)->bf16 | 2 aux+s*(.)->bf16 | 3 aux+s*(.)->f32
// ---------------------------------------------------------------------------
template <int EPI>
__global__ __launch_bounds__(256) void gemm_k(
    const __bf16* __restrict__ A, const __bf16* __restrict__ Bt,
    const float* __restrict__ bias, const __bf16* __restrict__ aux,
    const float* __restrict__ scal, void* __restrict__ out, int Ntot)
{
    constexpr int K = D_;
    __shared__ __align__(16) __bf16 As[2][128][64];  // 32 KB
    __shared__ __align__(16) __bf16 Bs[2][128][64];  // 32 KB

    const int tid = threadIdx.x, lane = tid & 63, wid = tid >> 6;
    const int wr = wid >> 1, wc = wid & 1;
    const int cpx = (int)gridDim.x >> 3;            // grid % 8 == 0 always
    const int bid = (int)blockIdx.x;
    const int wg = (bid & 7) * cpx + (bid >> 3);    // XCD-bijective swizzle
    const int m0 = (wg & 31) * 128;                 // M/128 == 32 (fixed)
    const int n0 = (wg >> 5) * 128;
    const int frow = lane & 15;
    const int kb = (lane >> 4) * 16;                // k-group byte offset
    char* cAs = (char*)As; char* cBs = (char*)Bs;

    f32x4 acc[4][4] = {};

    auto stage = [&](int buf, int k0) {             // 8 loads / thread
#pragma unroll
        for (int i = 0; i < 4; ++i) {
            const int o = tid * 16 + i * 4096;      // 16 KB tile half
            const int row = o >> 7;
            const int cb = (o & 127) ^ ((row & 7) << 4);
            async16(A + (size_t)(m0 + row) * K + k0 + (cb >> 1),
                    cAs + buf * 16384 + o);
            async16(Bt + (size_t)(n0 + row) * K + k0 + (cb >> 1),
                    cBs + buf * 16384 + o);
        }
    };

    auto compute = [&](int buf) {
        char* lA = cAs + buf * 16384;
        char* lB = cBs + buf * 16384;
#pragma unroll
        for (int kk = 0; kk < 2; ++kk) {
            bf16x8 af[4], bfr[4];
#pragma unroll
            for (int m = 0; m < 4; ++m) {
                const int r = wr * 64 + m * 16 + frow;
                af[m] = *(const bf16x8*)(lA + ((r * 128 + kk * 64 + kb) ^ ((r & 7) << 4)));
            }
#pragma unroll
            for (int n = 0; n < 4; ++n) {
                const int r = wc * 64 + n * 16 + frow;
                bfr[n] = *(const bf16x8*)(lB + ((r * 128 + kk * 64 + kb) ^ ((r & 7) << 4)));
            }
#pragma unroll
            for (int m = 0; m < 4; ++m)
#pragma unroll
                for (int n = 0; n < 4; ++n)
                    acc[m][n] = __builtin_amdgcn_mfma_f32_16x16x32_bf16(
                        af[m], bfr[n], acc[m][n], 0, 0, 0);
        }
    };

    stage(0, 0);
    stage(1, 64);
    WAITVM(8);                                  // buf0 complete (oldest 8)
    __builtin_amdgcn_sched_barrier(0);
    __builtin_amdgcn_s_barrier();

    for (int tp = 0; tp < 8; ++tp) {            // 16 K-steps, 2 per iter
        const int t0 = tp * 2;
        compute(0);
        __builtin_amdgcn_s_barrier();           // all waves done reading buf0
        if (t0 < 14) { stage(0, (t0 + 2) * 64); WAITVM(8); }  // tile t0+1 ready
        else         { WAITVM(0); }             // last tile (in buf1) ready
        __builtin_amdgcn_sched_barrier(0);
        __builtin_amdgcn_s_barrier();
        compute(1);
        __builtin_amdgcn_s_barrier();           // all waves done reading buf1
        if (t0 < 14) { stage(1, (t0 + 3) * 64); WAITVM(8); }  // tile t0+2 ready
        __builtin_amdgcn_sched_barrier(0);
        __builtin_amdgcn_s_barrier();
    }

    const float sv = (EPI >= 2) ? *scal : 0.f;
#pragma unroll
    for (int m = 0; m < 4; ++m) {
#pragma unroll
        for (int n = 0; n < 4; ++n) {
#pragma unroll
            for (int r = 0; r < 4; ++r) {
                const int row = m0 + wr * 64 + m * 16 + (lane >> 4) * 4 + r;
                const int col = n0 + wc * 64 + n * 16 + frow;
                const size_t idx = (size_t)row * Ntot + col;
                float v = acc[m][n][r] + bias[col];
                if constexpr (EPI == 0) {
                    ((__bf16*)out)[idx] = (__bf16)v;
                } else if constexpr (EPI == 1) {
                    v = v > 0.f ? v : 0.2f * v;
                    ((__bf16*)out)[idx] = (__bf16)v;
                } else if constexpr (EPI == 2) {
                    ((__bf16*)out)[idx] = (__bf16)((float)aux[idx] + sv * v);
                } else {
                    ((float*)out)[idx] = (float)aux[idx] + sv * v;
                }
            }
        }
    }
}

// ---------------------------------------------------------------------------
// Fused attention (elementwise sigmoid*tanh on logits — no softmax).
// Block = (q-tile 64, head, batch) decoded from a 1D XCD-swizzled grid of
// 1024 blocks (each XCD owns 4 full (b,h) pairs -> K/V fetched once/XCD).
// 4 waves x 16 q-rows. KVBLK=64, K/V double-buffered with counted vmcnt
// (4 loads per stage; WAITVM(4) one compute-phase after issue).
// Swapped QK^T (mfma(K,Q)) -> lane owns 4 consecutive keys -> packed b64
// P-writes; Ps wave-private. kt-loop unrolled x2 so all swizzled LDS
// addresses are compile-time. s_setprio(1) around MFMA clusters.
// ---------------------------------------------------------------------------
__global__ __launch_bounds__(256, 4) void attn_k(
    const __bf16* __restrict__ Q, const __bf16* __restrict__ Kmat,
    const __bf16* __restrict__ VT, __bf16* __restrict__ CTX, int ld)
{
    __shared__ __align__(16) __bf16 Ks[2][64][64];  // 16 KB [buf][key][hd]
    __shared__ __align__(16) __bf16 Vs[2][64][64];  // 16 KB [buf][d][key]
    __shared__ __align__(16) __bf16 Ps[64][64];     //  8 KB [q][key]

    const int tid = threadIdx.x, wid = tid >> 6, lane = tid & 63;
    const int bid = (int)blockIdx.x;
    const int wg = (bid & 7) * 128 + (bid >> 3);    // 1024 blocks, bijective
    const int qt = wg & 31, h = (wg >> 5) & 15, b = wg >> 9;
    const int q0 = qt * 64;
    const int frow = lane & 15, g = lane >> 4;
    const int kg8 = g * 8, kb = g * 16;
    const int qrow = wid * 16 + frow;               // this lane's q row

    const __bf16* qbase = Q    + (size_t)(b * S_ + q0) * ld + h * 64;
    const __bf16* kbase = Kmat + (size_t)b * S_ * ld + h * 64;
    const __bf16* vbase = VT   + (size_t)(b * H_ + h) * 64 * S_;

    bf16x8 qf[2];
#pragma unroll
    for (int kk = 0; kk < 2; ++kk)
        qf[kk] = *(const bf16x8*)(qbase + (size_t)qrow * ld + kk * 32 + kg8);
    __builtin_amdgcn_sched_barrier(0);   // pin qf loads before staging (vmcnt order)

    f32x4 octx[4] = {};
    char* cKs = (char*)Ks; char* cVs = (char*)Vs; char* lPs = (char*)Ps;

    auto stageKV = [&](int buf, int kt) {           // 4 loads / thread
#pragma unroll
        for (int i = 0; i < 2; ++i) {
            const int o = tid * 16 + i * 4096;      // 0..8KB
            const int row = o >> 7;
            const int cb = (o & 127) ^ ((row & 7) << 4);
            async16(kbase + (size_t)(kt + row) * ld + (cb >> 1),
                    cKs + buf * 8192 + o);
            async16(vbase + (size_t)row * S_ + kt + (cb >> 1),
                    cVs + buf * 8192 + o);
        }
    };

    auto computeTile = [&](char* lKs, char* lVs) {
        // ---- S^T = K Q^T: lane holds P[key=16n+4g+r][q=qrow]
        f32x4 scc[4] = {};
        __builtin_amdgcn_s_setprio(1);
#pragma unroll
        for (int kk = 0; kk < 2; ++kk) {
            bf16x8 kf[4];
#pragma unroll
            for (int n = 0; n < 4; ++n) {
                const int r = n * 16 + frow;
                kf[n] = *(const bf16x8*)(lKs + ((r * 128 + kk * 64 + kb) ^ ((r & 7) << 4)));
            }
#pragma unroll
            for (int n = 0; n < 4; ++n)
                scc[n] = __builtin_amdgcn_mfma_f32_16x16x32_bf16(
                    kf[n], qf[kk], scc[n], 0, 0, 0);
        }
        __builtin_amdgcn_s_setprio(0);
        // ---- activation + packed b64 P-write (4 consecutive keys/write)
#pragma unroll
        for (int n = 0; n < 4; ++n) {
            bf16x4 pw;
#pragma unroll
            for (int r = 0; r < 4; ++r) pw[r] = (__bf16)actf(scc[n][r]);
            *(bf16x4*)(lPs + ((qrow * 128 + n * 32 + g * 8) ^ ((qrow & 7) << 4))) = pw;
        }
        // ---- ctx += P @ V  (wave-private P rows: no barrier)
        __builtin_amdgcn_s_setprio(1);
#pragma unroll
        for (int ks = 0; ks < 2; ++ks) {
            bf16x8 pf = *(const bf16x8*)(lPs +
                ((qrow * 128 + ks * 64 + kb) ^ ((qrow & 7) << 4)));
            bf16x8 vf[4];
#pragma unroll
            for (int nd = 0; nd < 4; ++nd) {
                const int rd = nd * 16 + frow;
                vf[nd] = *(const bf16x8*)(lVs + ((rd * 128 + ks * 64 + kb) ^ ((rd & 7) << 4)));
            }
#pragma unroll
            for (int nd = 0; nd < 4; ++nd)
                octx[nd] = __builtin_amdgcn_mfma_f32_16x16x32_bf16(
                    pf, vf[nd], octx[nd], 0, 0, 0);
        }
        __builtin_amdgcn_s_setprio(0);
    };

    stageKV(0, 0);
    stageKV(1, 64);
    WAITVM(4);                                  // buf0 ready (oldest 4)
    __builtin_amdgcn_sched_barrier(0);
    __builtin_amdgcn_s_barrier();

    for (int it = 0; it < 16; ++it) {           // 32 key-tiles, 2 per iter
        const int kt0 = it * 128;
        computeTile(cKs, cVs);                  // buf0 = tile kt0
        __builtin_amdgcn_s_barrier();           // all waves done with buf0
        if (it < 15) { stageKV(0, kt0 + 128); WAITVM(4); }
        else         { WAITVM(0); }             // last tile (buf1) ready
        __builtin_amdgcn_sched_barrier(0);
        __builtin_amdgcn_s_barrier();
        computeTile(cKs + 8192, cVs + 8192);    // buf1 = tile kt0+64
        __builtin_amdgcn_s_barrier();
        if (it < 15) { stageKV(1, kt0 + 192); WAITVM(4); }
        __builtin_amdgcn_sched_barrier(0);
        __builtin_amdgcn_s_barrier();
    }

#pragma unroll
    for (int nd = 0; nd < 4; ++nd)
#pragma unroll
        for (int r = 0; r < 4; ++r) {
            const int row = q0 + wid * 16 + g * 4 + r;
            const int col = h * 64 + nd * 16 + frow;
            CTX[(size_t)(b * S_ + row) * D_ + col] = (__bf16)octx[nd][r];
        }
}

// ---------------------------------------------------------------------------
struct WPack { const float* w[7]; };

__global__ __launch_bounds__(256) void conv_transpose_w(WPack p, __bf16* out) {
    __shared__ float t[32][33];
    const float* W = p.w[blockIdx.z];
    __bf16* o = out + (size_t)blockIdx.z * D_ * D_;
    const int c0 = blockIdx.x * 32, r0 = blockIdx.y * 32;
    const int tx = threadIdx.x, ty = threadIdx.y;
#pragma unroll
    for (int i = 0; i < 4; ++i)
        t[ty + i * 8][tx] = W[(size_t)(r0 + ty + i * 8) * D_ + c0 + tx];
    __syncthreads();
#pragma unroll
    for (int i = 0; i < 4; ++i)
        o[(size_t)(c0 + ty + i * 8) * D_ + r0 + tx] = (__bf16)t[tx][ty + i * 8];
}

__global__ __launch_bounds__(256) void conv_bf16(
    const float* __restrict__ in, __bf16* __restrict__ out, int n4)
{
    const int i = blockIdx.x * blockDim.x + threadIdx.x;
    if (i < n4) {
        f32x4 v = ((const f32x4*)in)[i];
        bf16x4 o;
        o[0] = (__bf16)v[0]; o[1] = (__bf16)v[1];
        o[2] = (__bf16)v[2]; o[3] = (__bf16)v[3];
        ((bf16x4*)out)[i] = o;
    }
}

__global__ __launch_bounds__(256) void bcat_k(
    const float* __restrict__ bq, const float* __restrict__ bk,
    const float* __restrict__ bv, float* __restrict__ o)
{
    const int i = blockIdx.x * 256 + threadIdx.x;   // 0..3071
    o[i] = i < 1024 ? bq[i] : (i < 2048 ? bk[i - 1024] : bv[i - 2048]);
}

// V rows of QKV [B*S][ld] -> VT[(b*D + col)][S]
__global__ __launch_bounds__(256) void transpose_v(
    const __bf16* __restrict__ V, __bf16* __restrict__ VT, int ld)
{
    __shared__ __bf16 t[32][33];
    const int s0 = blockIdx.x * 32, c0 = blockIdx.y * 32, b = blockIdx.z;
    const int tx = threadIdx.x, ty = threadIdx.y;
#pragma unroll
    for (int i = 0; i < 4; ++i)
        t[ty + i * 8][tx] = V[(size_t)(b * S_ + s0 + ty + i * 8) * ld + c0 + tx];
    __syncthreads();
#pragma unroll
    for (int i = 0; i < 4; ++i)
        VT[(size_t)(b * D_ + c0 + ty + i * 8) * S_ + s0 + tx] = t[tx][ty + i * 8];
}

// ---------------------------------------------------------------------------
extern "C" void kernel_launch(void* const* d_in, const int* in_sizes, int n_in,
                              void* d_out, int out_size, void* d_ws, size_t ws_size,
                              hipStream_t stream) {
    const float* x    = (const float*)d_in[0];
    const float* W_in = (const float*)d_in[1];
    const float* b_in = (const float*)d_in[2];
    const float* Wq   = (const float*)d_in[3];
    const float* bq   = (const float*)d_in[4];
    const float* Wk   = (const float*)d_in[5];
    const float* bk   = (const float*)d_in[6];
    const float* Wv   = (const float*)d_in[7];
    const float* bv   = (const float*)d_in[8];
    const float* Wo   = (const float*)d_in[9];
    const float* bo   = (const float*)d_in[10];
    const float* W1   = (const float*)d_in[11];
    const float* b1   = (const float*)d_in[12];
    const float* W2   = (const float*)d_in[13];
    const float* b2   = (const float*)d_in[14];
    const float* s_att = (const float*)d_in[15];
    const float* s_ff  = (const float*)d_in[16];

    char* ws = (char*)d_ws;
    const size_t WB = (size_t)D_ * D_ * 2;       // 2 MB / bf16 weight
    const size_t MB = (size_t)M_ * D_ * 2;       // 8 MB / bf16 activation
    __bf16* WT   = (__bf16*)(ws);                           // 14 MB
    __bf16* Hb   = (__bf16*)(ws + 7 * WB);                  // 8 MB
    __bf16* QKVb = (__bf16*)(ws + 7 * WB + MB);             // 24 MB
    __bf16* VTb  = (__bf16*)(ws + 7 * WB + 4 * MB);         // 8 MB
    __bf16* Xb   = (__bf16*)(ws + 7 * WB + 5 * MB);         // 8 MB
    float*  bcat = (float*)VTb;       // alias: bcat dead before VTb written
    __bf16* CTXb = Xb;                // x dead after first GEMM
    __bf16* LATb = QKVb;              // qkv dead after attention
    __bf16* FF1b = QKVb + (size_t)M_ * D_;
    auto WTi = [&](int i) { return WT + (size_t)i * D_ * D_; };

    WPack wp;
    wp.w[0] = W_in; wp.w[1] = Wq; wp.w[2] = Wk; wp.w[3] = Wv;
    wp.w[4] = Wo;   wp.w[5] = W1; wp.w[6] = W2;
    conv_transpose_w<<<dim3(32, 32, 7), dim3(32, 8), 0, stream>>>(wp, WT);
    conv_bf16<<<dim3(4096), dim3(256), 0, stream>>>(x, Xb, (M_ * D_) / 4);
    bcat_k<<<dim3(12), dim3(256), 0, stream>>>(bq, bk, bv, bcat);

    // h = x @ W_in + b_in            (grid 32x8 = 256 blocks)
    gemm_k<0><<<dim3(256), dim3(256), 0, stream>>>(
        Xb, WTi(0), b_in, nullptr, nullptr, Hb, D_);
    // qkv = h @ [Wq|Wk|Wv] + bcat    (N=3072, 32x24 = 768 blocks)
    gemm_k<0><<<dim3(768), dim3(256), 0, stream>>>(
        Hb, WTi(1), bcat, nullptr, nullptr, QKVb, 3 * D_);
    transpose_v<<<dim3(64, 32, 2), dim3(32, 8), 0, stream>>>(
        QKVb + 2 * D_, VTb, 3 * D_);
    attn_k<<<dim3(1024), dim3(256), 0, stream>>>(
        QKVb, QKVb + D_, VTb, CTXb, 3 * D_);
    // latent = h + s_att * (ctx @ Wo + bo)
    gemm_k<2><<<dim3(256), dim3(256), 0, stream>>>(
        CTXb, WTi(4), bo, Hb, s_att, LATb, D_);
    // ff1 = leaky_relu(latent @ W1 + b1)
    gemm_k<1><<<dim3(256), dim3(256), 0, stream>>>(
        LATb, WTi(5), b1, nullptr, nullptr, FF1b, D_);
    // out = latent + s_ff * (ff1 @ W2 + b2)  (f32)
    gemm_k<3><<<dim3(256), dim3(256), 0, stream>>>(
        FF1b, WTi(6), b2, LATb, s_ff, d_out, D_);
}

// Round 7
// 289.603 us; speedup vs baseline: 1.3328x; 1.0037x over previous
//
#include <hip/hip_runtime.h>
#include <cstdint>
#include <cstddef>

// ---------------------------------------------------------------------------
// TransformerLayer forward on MI355X (gfx950), bf16 MFMA pipeline.
// B=2, S=2048, D=1024, H=16, HD=64.  M = B*S = 4096 rows.
// Round 7: GEMM -> BM=128 x BN=64, BK=64, 4 waves x (64x32), 48 KB LDS dbuf,
// counted vmcnt(6); grid 512 (N=1024) / 1536 (QKV) = 2-6 blocks/CU so
// independent blocks hide the staging latency (m114 mechanism).
// Attention unchanged from round 6 (XCD swizzle, FETCH already near-ideal).
// ---------------------------------------------------------------------------

#define B_ 2
#define S_ 2048
#define D_ 1024
#define H_ 16
#define M_ 4096

typedef __attribute__((ext_vector_type(4))) float  f32x4;
typedef __attribute__((ext_vector_type(8))) __bf16 bf16x8;
typedef __attribute__((ext_vector_type(4))) __bf16 bf16x4;

#define WAITVM(N) asm volatile("s_waitcnt vmcnt(" #N ")" ::: "memory")

__device__ __forceinline__ void async16(const void* g, void* l) {
    __builtin_amdgcn_global_load_lds(
        (__attribute__((address_space(1))) void*)(g),
        (__attribute__((address_space(3))) void*)(l), 16, 0, 0);
}

// sigmoid(z)*tanh(z) == (1-u)/(1+u^2), u = exp(-z), z = s/32.
// u = exp2(s * -log2(e)/32); clamp exponent to avoid inf/inf.
__device__ __forceinline__ float actf(float s) {
    float t = fminf(s * -0.045084223f, 21.6f);
    float u = __builtin_amdgcn_exp2f(t);
    return (1.f - u) * __builtin_amdgcn_rcpf(1.f + u * u);
}

// ---------------------------------------------------------------------------
// GEMM: C[M][Ntot] = epilogue(A[M][1024] @ Bt[Ntot][1024]^T + bias)
// Tile 128x64, BK=64, 4 waves (2x2), each wave 64x32 (acc 4x2).
// LDS 48 KB double-buffered; counted vmcnt: stage(next) issued post-barrier,
// WAITVM(6) waits only for the PREVIOUS stage (one compute phase old).
// 2-6 independent blocks/CU overlap the residual stall (m114).
// LDS XOR-swizzled (row&7)<<4; pre-swizzled global source (both-sides rule).
// M fixed 4096 -> 32 m-tiles; 1D grid with XCD-bijective swizzle.
// EPI: 0 bias->bf16 | 1 leaky(0.2)->bf16 | 2 aux+s*(.)->bf16 | 3 aux+s*(.)->f32
// ---------------------------------------------------------------------------
template <int EPI>
__global__ __launch_bounds__(256) void gemm_k(
    const __bf16* __restrict__ A, const __bf16* __restrict__ Bt,
    const float* __restrict__ bias, const __bf16* __restrict__ aux,
    const float* __restrict__ scal, void* __restrict__ out, int Ntot)
{
    constexpr int K = D_;
    __shared__ __align__(16) __bf16 As[2][128][64];  // 32 KB
    __shared__ __align__(16) __bf16 Bs[2][64][64];   // 16 KB

    const int tid = threadIdx.x, lane = tid & 63, wid = tid >> 6;
    const int wr = wid >> 1, wc = wid & 1;
    const int cpx = (int)gridDim.x >> 3;            // grid % 8 == 0 always
    const int bid = (int)blockIdx.x;
    const int wg = (bid & 7) * cpx + (bid >> 3);    // XCD-bijective swizzle
    const int m0 = (wg & 31) * 128;                 // M/128 == 32 (fixed)
    const int n0 = (wg >> 5) * 64;
    const int frow = lane & 15;
    const int kb = (lane >> 4) * 16;                // k-group byte offset
    char* cAs = (char*)As; char* cBs = (char*)Bs;

    f32x4 acc[4][2] = {};

    auto stage = [&](int buf, int k0) {             // 6 loads / thread
#pragma unroll
        for (int i = 0; i < 4; ++i) {               // A tile: 16 KB
            const int o = tid * 16 + i * 4096;
            const int row = o >> 7;
            const int cb = (o & 127) ^ ((row & 7) << 4);
            async16(A + (size_t)(m0 + row) * K + k0 + (cb >> 1),
                    cAs + buf * 16384 + o);
        }
#pragma unroll
        for (int i = 0; i < 2; ++i) {               // B tile: 8 KB
            const int o = tid * 16 + i * 4096;
            const int row = o >> 7;
            const int cb = (o & 127) ^ ((row & 7) << 4);
            async16(Bt + (size_t)(n0 + row) * K + k0 + (cb >> 1),
                    cBs + buf * 8192 + o);
        }
    };

    auto compute = [&](int buf) {
        char* lA = cAs + buf * 16384;
        char* lB = cBs + buf * 8192;
#pragma unroll
        for (int kk = 0; kk < 2; ++kk) {
            bf16x8 af[4], bfr[2];
#pragma unroll
            for (int m = 0; m < 4; ++m) {
                const int r = wr * 64 + m * 16 + frow;
                af[m] = *(const bf16x8*)(lA + ((r * 128 + kk * 64 + kb) ^ ((r & 7) << 4)));
            }
#pragma unroll
            for (int n = 0; n < 2; ++n) {
                const int r = wc * 32 + n * 16 + frow;
                bfr[n] = *(const bf16x8*)(lB + ((r * 128 + kk * 64 + kb) ^ ((r & 7) << 4)));
            }
#pragma unroll
            for (int m = 0; m < 4; ++m)
#pragma unroll
                for (int n = 0; n < 2; ++n)
                    acc[m][n] = __builtin_amdgcn_mfma_f32_16x16x32_bf16(
                        af[m], bfr[n], acc[m][n], 0, 0, 0);
        }
    };

    stage(0, 0);
    stage(1, 64);
    WAITVM(6);                                  // buf0 complete (oldest 6)
    __builtin_amdgcn_sched_barrier(0);
    __builtin_amdgcn_s_barrier();

    for (int tp = 0; tp < 8; ++tp) {            // 16 K-steps, 2 per iter
        const int t0 = tp * 2;
        compute(0);
        __builtin_amdgcn_s_barrier();           // all waves done reading buf0
        if (t0 < 14) { stage(0, (t0 + 2) * 64); WAITVM(6); }  // buf1 ready
        else         { WAITVM(0); }             // last tile (in buf1) ready
        __builtin_amdgcn_sched_barrier(0);
        __builtin_amdgcn_s_barrier();
        compute(1);
        __builtin_amdgcn_s_barrier();           // all waves done reading buf1
        if (t0 < 14) { stage(1, (t0 + 3) * 64); WAITVM(6); }  // buf0 ready
        __builtin_amdgcn_sched_barrier(0);
        __builtin_amdgcn_s_barrier();
    }

    const float sv = (EPI >= 2) ? *scal : 0.f;
#pragma unroll
    for (int m = 0; m < 4; ++m) {
#pragma unroll
        for (int n = 0; n < 2; ++n) {
#pragma unroll
            for (int r = 0; r < 4; ++r) {
                const int row = m0 + wr * 64 + m * 16 + (lane >> 4) * 4 + r;
                const int col = n0 + wc * 32 + n * 16 + frow;
                const size_t idx = (size_t)row * Ntot + col;
                float v = acc[m][n][r] + bias[col];
                if constexpr (EPI == 0) {
                    ((__bf16*)out)[idx] = (__bf16)v;
                } else if constexpr (EPI == 1) {
                    v = v > 0.f ? v : 0.2f * v;
                    ((__bf16*)out)[idx] = (__bf16)v;
                } else if constexpr (EPI == 2) {
                    ((__bf16*)out)[idx] = (__bf16)((float)aux[idx] + sv * v);
                } else {
                    ((float*)out)[idx] = (float)aux[idx] + sv * v;
                }
            }
        }
    }
}

// ---------------------------------------------------------------------------
// Fused attention (elementwise sigmoid*tanh on logits — no softmax).
// Unchanged from round 6: XCD-bijective 1D grid (1024 blocks), 4 waves x
// 16 q-rows, KVBLK=64 dbuf with counted vmcnt, swapped QK^T + packed b64
// P-writes, wave-private Ps, s_setprio(1) around MFMA clusters.
// ---------------------------------------------------------------------------
__global__ __launch_bounds__(256, 4) void attn_k(
    const __bf16* __restrict__ Q, const __bf16* __restrict__ Kmat,
    const __bf16* __restrict__ VT, __bf16* __restrict__ CTX, int ld)
{
    __shared__ __align__(16) __bf16 Ks[2][64][64];  // 16 KB [buf][key][hd]
    __shared__ __align__(16) __bf16 Vs[2][64][64];  // 16 KB [buf][d][key]
    __shared__ __align__(16) __bf16 Ps[64][64];     //  8 KB [q][key]

    const int tid = threadIdx.x, wid = tid >> 6, lane = tid & 63;
    const int bid = (int)blockIdx.x;
    const int wg = (bid & 7) * 128 + (bid >> 3);    // 1024 blocks, bijective
    const int qt = wg & 31, h = (wg >> 5) & 15, b = wg >> 9;
    const int q0 = qt * 64;
    const int frow = lane & 15, g = lane >> 4;
    const int kg8 = g * 8, kb = g * 16;
    const int qrow = wid * 16 + frow;               // this lane's q row

    const __bf16* qbase = Q    + (size_t)(b * S_ + q0) * ld + h * 64;
    const __bf16* kbase = Kmat + (size_t)b * S_ * ld + h * 64;
    const __bf16* vbase = VT   + (size_t)(b * H_ + h) * 64 * S_;

    bf16x8 qf[2];
#pragma unroll
    for (int kk = 0; kk < 2; ++kk)
        qf[kk] = *(const bf16x8*)(qbase + (size_t)qrow * ld + kk * 32 + kg8);
    __builtin_amdgcn_sched_barrier(0);   // pin qf loads before staging (vmcnt order)

    f32x4 octx[4] = {};
    char* cKs = (char*)Ks; char* cVs = (char*)Vs; char* lPs = (char*)Ps;

    auto stageKV = [&](int buf, int kt) {           // 4 loads / thread
#pragma unroll
        for (int i = 0; i < 2; ++i) {
            const int o = tid * 16 + i * 4096;      // 0..8KB
            const int row = o >> 7;
            const int cb = (o & 127) ^ ((row & 7) << 4);
            async16(kbase + (size_t)(kt + row) * ld + (cb >> 1),
                    cKs + buf * 8192 + o);
            async16(vbase + (size_t)row * S_ + kt + (cb >> 1),
                    cVs + buf * 8192 + o);
        }
    };

    auto computeTile = [&](char* lKs, char* lVs) {
        // ---- S^T = K Q^T: lane holds P[key=16n+4g+r][q=qrow]
        f32x4 scc[4] = {};
        __builtin_amdgcn_s_setprio(1);
#pragma unroll
        for (int kk = 0; kk < 2; ++kk) {
            bf16x8 kf[4];
#pragma unroll
            for (int n = 0; n < 4; ++n) {
                const int r = n * 16 + frow;
                kf[n] = *(const bf16x8*)(lKs + ((r * 128 + kk * 64 + kb) ^ ((r & 7) << 4)));
            }
#pragma unroll
            for (int n = 0; n < 4; ++n)
                scc[n] = __builtin_amdgcn_mfma_f32_16x16x32_bf16(
                    kf[n], qf[kk], scc[n], 0, 0, 0);
        }
        __builtin_amdgcn_s_setprio(0);
        // ---- activation + packed b64 P-write (4 consecutive keys/write)
#pragma unroll
        for (int n = 0; n < 4; ++n) {
            bf16x4 pw;
#pragma unroll
            for (int r = 0; r < 4; ++r) pw[r] = (__bf16)actf(scc[n][r]);
            *(bf16x4*)(lPs + ((qrow * 128 + n * 32 + g * 8) ^ ((qrow & 7) << 4))) = pw;
        }
        // ---- ctx += P @ V  (wave-private P rows: no barrier)
        __builtin_amdgcn_s_setprio(1);
#pragma unroll
        for (int ks = 0; ks < 2; ++ks) {
            bf16x8 pf = *(const bf16x8*)(lPs +
                ((qrow * 128 + ks * 64 + kb) ^ ((qrow & 7) << 4)));
            bf16x8 vf[4];
#pragma unroll
            for (int nd = 0; nd < 4; ++nd) {
                const int rd = nd * 16 + frow;
                vf[nd] = *(const bf16x8*)(lVs + ((rd * 128 + ks * 64 + kb) ^ ((rd & 7) << 4)));
            }
#pragma unroll
            for (int nd = 0; nd < 4; ++nd)
                octx[nd] = __builtin_amdgcn_mfma_f32_16x16x32_bf16(
                    pf, vf[nd], octx[nd], 0, 0, 0);
        }
        __builtin_amdgcn_s_setprio(0);
    };

    stageKV(0, 0);
    stageKV(1, 64);
    WAITVM(4);                                  // buf0 ready (oldest 4)
    __builtin_amdgcn_sched_barrier(0);
    __builtin_amdgcn_s_barrier();

    for (int it = 0; it < 16; ++it) {           // 32 key-tiles, 2 per iter
        const int kt0 = it * 128;
        computeTile(cKs, cVs);                  // buf0 = tile kt0
        __builtin_amdgcn_s_barrier();           // all waves done with buf0
        if (it < 15) { stageKV(0, kt0 + 128); WAITVM(4); }
        else         { WAITVM(0); }             // last tile (buf1) ready
        __builtin_amdgcn_sched_barrier(0);
        __builtin_amdgcn_s_barrier();
        computeTile(cKs + 8192, cVs + 8192);    // buf1 = tile kt0+64
        __builtin_amdgcn_s_barrier();
        if (it < 15) { stageKV(1, kt0 + 192); WAITVM(4); }
        __builtin_amdgcn_sched_barrier(0);
        __builtin_amdgcn_s_barrier();
    }

#pragma unroll
    for (int nd = 0; nd < 4; ++nd)
#pragma unroll
        for (int r = 0; r < 4; ++r) {
            const int row = q0 + wid * 16 + g * 4 + r;
            const int col = h * 64 + nd * 16 + frow;
            CTX[(size_t)(b * S_ + row) * D_ + col] = (__bf16)octx[nd][r];
        }
}

// ---------------------------------------------------------------------------
struct WPack { const float* w[7]; };

__global__ __launch_bounds__(256) void conv_transpose_w(WPack p, __bf16* out) {
    __shared__ float t[32][33];
    const float* W = p.w[blockIdx.z];
    __bf16* o = out + (size_t)blockIdx.z * D_ * D_;
    const int c0 = blockIdx.x * 32, r0 = blockIdx.y * 32;
    const int tx = threadIdx.x, ty = threadIdx.y;
#pragma unroll
    for (int i = 0; i < 4; ++i)
        t[ty + i * 8][tx] = W[(size_t)(r0 + ty + i * 8) * D_ + c0 + tx];
    __syncthreads();
#pragma unroll
    for (int i = 0; i < 4; ++i)
        o[(size_t)(c0 + ty + i * 8) * D_ + r0 + tx] = (__bf16)t[tx][ty + i * 8];
}

__global__ __launch_bounds__(256) void conv_bf16(
    const float* __restrict__ in, __bf16* __restrict__ out, int n4)
{
    const int i = blockIdx.x * blockDim.x + threadIdx.x;
    if (i < n4) {
        f32x4 v = ((const f32x4*)in)[i];
        bf16x4 o;
        o[0] = (__bf16)v[0]; o[1] = (__bf16)v[1];
        o[2] = (__bf16)v[2]; o[3] = (__bf16)v[3];
        ((bf16x4*)out)[i] = o;
    }
}

__global__ __launch_bounds__(256) void bcat_k(
    const float* __restrict__ bq, const float* __restrict__ bk,
    const float* __restrict__ bv, float* __restrict__ o)
{
    const int i = blockIdx.x * 256 + threadIdx.x;   // 0..3071
    o[i] = i < 1024 ? bq[i] : (i < 2048 ? bk[i - 1024] : bv[i - 2048]);
}

// V rows of QKV [B*S][ld] -> VT[(b*D + col)][S]
__global__ __launch_bounds__(256) void transpose_v(
    const __bf16* __restrict__ V, __bf16* __restrict__ VT, int ld)
{
    __shared__ __bf16 t[32][33];
    const int s0 = blockIdx.x * 32, c0 = blockIdx.y * 32, b = blockIdx.z;
    const int tx = threadIdx.x, ty = threadIdx.y;
#pragma unroll
    for (int i = 0; i < 4; ++i)
        t[ty + i * 8][tx] = V[(size_t)(b * S_ + s0 + ty + i * 8) * ld + c0 + tx];
    __syncthreads();
#pragma unroll
    for (int i = 0; i < 4; ++i)
        VT[(size_t)(b * D_ + c0 + ty + i * 8) * S_ + s0 + tx] = t[tx][ty + i * 8];
}

// ---------------------------------------------------------------------------
extern "C" void kernel_launch(void* const* d_in, const int* in_sizes, int n_in,
                              void* d_out, int out_size, void* d_ws, size_t ws_size,
                              hipStream_t stream) {
    const float* x    = (const float*)d_in[0];
    const float* W_in = (const float*)d_in[1];
    const float* b_in = (const float*)d_in[2];
    const float* Wq   = (const float*)d_in[3];
    const float* bq   = (const float*)d_in[4];
    const float* Wk   = (const float*)d_in[5];
    const float* bk   = (const float*)d_in[6];
    const float* Wv   = (const float*)d_in[7];
    const float* bv   = (const float*)d_in[8];
    const float* Wo   = (const float*)d_in[9];
    const float* bo   = (const float*)d_in[10];
    const float* W1   = (const float*)d_in[11];
    const float* b1   = (const float*)d_in[12];
    const float* W2   = (const float*)d_in[13];
    const float* b2   = (const float*)d_in[14];
    const float* s_att = (const float*)d_in[15];
    const float* s_ff  = (const float*)d_in[16];

    char* ws = (char*)d_ws;
    const size_t WB = (size_t)D_ * D_ * 2;       // 2 MB / bf16 weight
    const size_t MB = (size_t)M_ * D_ * 2;       // 8 MB / bf16 activation
    __bf16* WT   = (__bf16*)(ws);                           // 14 MB
    __bf16* Hb   = (__bf16*)(ws + 7 * WB);                  // 8 MB
    __bf16* QKVb = (__bf16*)(ws + 7 * WB + MB);             // 24 MB
    __bf16* VTb  = (__bf16*)(ws + 7 * WB + 4 * MB);         // 8 MB
    __bf16* Xb   = (__bf16*)(ws + 7 * WB + 5 * MB);         // 8 MB
    float*  bcat = (float*)VTb;       // alias: bcat dead before VTb written
    __bf16* CTXb = Xb;                // x dead after first GEMM
    __bf16* LATb = QKVb;              // qkv dead after attention
    __bf16* FF1b = QKVb + (size_t)M_ * D_;
    auto WTi = [&](int i) { return WT + (size_t)i * D_ * D_; };

    WPack wp;
    wp.w[0] = W_in; wp.w[1] = Wq; wp.w[2] = Wk; wp.w[3] = Wv;
    wp.w[4] = Wo;   wp.w[5] = W1; wp.w[6] = W2;
    conv_transpose_w<<<dim3(32, 32, 7), dim3(32, 8), 0, stream>>>(wp, WT);
    conv_bf16<<<dim3(4096), dim3(256), 0, stream>>>(x, Xb, (M_ * D_) / 4);
    bcat_k<<<dim3(12), dim3(256), 0, stream>>>(bq, bk, bv, bcat);

    // h = x @ W_in + b_in            (32 m x 16 n = 512 blocks, 2/CU)
    gemm_k<0><<<dim3(512), dim3(256), 0, stream>>>(
        Xb, WTi(0), b_in, nullptr, nullptr, Hb, D_);
    // qkv = h @ [Wq|Wk|Wv] + bcat    (N=3072: 32 x 48 = 1536 blocks)
    gemm_k<0><<<dim3(1536), dim3(256), 0, stream>>>(
        Hb, WTi(1), bcat, nullptr, nullptr, QKVb, 3 * D_);
    transpose_v<<<dim3(64, 32, 2), dim3(32, 8), 0, stream>>>(
        QKVb + 2 * D_, VTb, 3 * D_);
    attn_k<<<dim3(1024), dim3(256), 0, stream>>>(
        QKVb, QKVb + D_, VTb, CTXb, 3 * D_);
    // latent = h + s_att * (ctx @ Wo + bo)
    gemm_k<2><<<dim3(512), dim3(256), 0, stream>>>(
        CTXb, WTi(4), bo, Hb, s_att, LATb, D_);
    // ff1 = leaky_relu(latent @ W1 + b1)
    gemm_k<1><<<dim3(512), dim3(256), 0, stream>>>(
        LATb, WTi(5), b1, nullptr, nullptr, FF1b, D_);
    // out = latent + s_ff * (ff1 @ W2 + b2)  (f32)
    gemm_k<3><<<dim3(512), dim3(256), 0, stream>>>(
        FF1b, WTi(6), b2, LATb, s_ff, d_out, D_);
}